// Round 2
// baseline (263.468 us; speedup 1.0000x reference)
//
#include <hip/hip_runtime.h>
#include <hip/hip_bf16.h>

// ---------------------------------------------------------------------------
// 2-layer GCN (PyG GCNConv semantics):
//   deg[i]  = in-degree(i) + 1 (self loop);  dinv = rsqrt(deg)
//   hs      = (x @ W) * dinv[row]
//   out[d]  = dinv[d] * ( sum_{(s,d) in E} hs[s] + hs[d] ) + b    (+ relu L1)
// Pipeline: count -> scan -> CSR fill -> gemm1 -> agg1(relu) -> gemm2 -> agg2
// NOTE: harness passes integer inputs as int32 (edge_index int64 -> int*).
// ---------------------------------------------------------------------------

__global__ __launch_bounds__(256) void count_k(const int* __restrict__ dst,
                                               int* __restrict__ counts, int E) {
    int e = blockIdx.x * 256 + threadIdx.x;
    if (e < E) atomicAdd(&counts[dst[e]], 1);
}

// Block-level exclusive scan: each block handles 1024 elements (4/thread).
// Also computes dinv[i] = rsqrt(counts[i] + 1).
__global__ __launch_bounds__(256) void scan1_k(const int* __restrict__ counts,
                                               int* __restrict__ offsets,
                                               int* __restrict__ bsums,
                                               float* __restrict__ dinv, int n) {
    __shared__ int sdata[256];
    int t = threadIdx.x;
    int base = blockIdx.x * 1024 + t * 4;
    int v[4];
    int s = 0;
#pragma unroll
    for (int i = 0; i < 4; ++i) {
        int idx = base + i;
        int c = (idx < n) ? counts[idx] : 0;
        v[i] = c;
        s += c;
        if (idx < n) dinv[idx] = rsqrtf((float)(c + 1));
    }
    sdata[t] = s;
    __syncthreads();
#pragma unroll
    for (int off = 1; off < 256; off <<= 1) {
        int x = 0;
        if (t >= off) x = sdata[t - off];
        __syncthreads();
        sdata[t] += x;
        __syncthreads();
    }
    int run = sdata[t] - s;  // exclusive prefix of this thread's chunk
#pragma unroll
    for (int i = 0; i < 4; ++i) {
        int idx = base + i;
        if (idx < n) offsets[idx] = run;
        run += v[i];
    }
    if (t == 255) bsums[blockIdx.x] = sdata[255];
}

// Single-block exclusive scan of the (<=64) block sums; writes offsets[n]=total.
__global__ __launch_bounds__(64) void scan2_k(int* __restrict__ bsums,
                                              int* __restrict__ offsets,
                                              int nb, int n) {
    __shared__ int sb[64];
    int t = threadIdx.x;
    int v = (t < nb) ? bsums[t] : 0;
    sb[t] = v;
    __syncthreads();
#pragma unroll
    for (int off = 1; off < 64; off <<= 1) {
        int x = 0;
        if (t >= off) x = sb[t - off];
        __syncthreads();
        sb[t] += x;
        __syncthreads();
    }
    if (t < nb) bsums[t] = sb[t] - v;      // exclusive
    if (t == nb - 1) offsets[n] = sb[t];   // total edge count
}

__global__ __launch_bounds__(256) void scan3_k(int* __restrict__ offsets,
                                               const int* __restrict__ bsums, int n) {
    int add = bsums[blockIdx.x];
    int base = blockIdx.x * 1024 + threadIdx.x * 4;
#pragma unroll
    for (int i = 0; i < 4; ++i) {
        int idx = base + i;
        if (idx < n) offsets[idx] += add;
    }
}

__global__ __launch_bounds__(256) void fill_k(const int* __restrict__ src,
                                              const int* __restrict__ dst,
                                              const int* __restrict__ offsets,
                                              int* __restrict__ cursor,
                                              int* __restrict__ adj, int E) {
    int e = blockIdx.x * 256 + threadIdx.x;
    if (e < E) {
        int d = dst[e];
        int pos = atomicAdd(&cursor[d], 1);
        adj[offsets[d] + pos] = src[e];
    }
}

// GEMM: Hout[row][c] = dinv[row] * sum_k X[row][k] * W[k][c]
// Block: 256 threads, BM=64 rows, full K=128 in LDS, 4-col x ROWS register tile.
template <int NOUT>
__global__ __launch_bounds__(256) void gemm_scale_k(const float* __restrict__ X,
                                                    const float* __restrict__ W,
                                                    const float* __restrict__ dinv,
                                                    float* __restrict__ Hout, int M) {
    constexpr int K = 128;
    constexpr int BM = 64;
    constexpr int COLCH = NOUT / 4;    // float4 column chunks: 32 or 16
    constexpr int RG = 256 / COLCH;    // row groups: 8 or 16
    constexpr int ROWS = BM / RG;      // rows per thread: 8 or 4
    __shared__ float xs[BM][K];

    int t = threadIdx.x;
    int brow = blockIdx.x * BM;

    // Stage x tile (64x128 = 2048 float4, 8 per thread), zero-pad tail rows.
    for (int i = t; i < BM * (K / 4); i += 256) {
        int row = i / (K / 4);
        int c4 = i % (K / 4);
        float4 v = make_float4(0.f, 0.f, 0.f, 0.f);
        int gr = brow + row;
        if (gr < M) v = *(const float4*)(X + (size_t)gr * K + c4 * 4);
        *(float4*)(&xs[row][c4 * 4]) = v;
    }
    __syncthreads();

    int cc = t % COLCH;
    int rg = t / COLCH;

    float acc[ROWS][4];
#pragma unroll
    for (int r = 0; r < ROWS; ++r) {
        acc[r][0] = 0.f; acc[r][1] = 0.f; acc[r][2] = 0.f; acc[r][3] = 0.f;
    }

    for (int k4 = 0; k4 < K / 4; ++k4) {
        float4 xv[ROWS];
#pragma unroll
        for (int r = 0; r < ROWS; ++r)
            xv[r] = *(const float4*)(&xs[rg * ROWS + r][k4 * 4]);
#pragma unroll
        for (int kk = 0; kk < 4; ++kk) {
            float4 w = *(const float4*)(W + (size_t)(k4 * 4 + kk) * NOUT + cc * 4);
#pragma unroll
            for (int r = 0; r < ROWS; ++r) {
                float xvk = ((const float*)&xv[r])[kk];
                acc[r][0] += xvk * w.x;
                acc[r][1] += xvk * w.y;
                acc[r][2] += xvk * w.z;
                acc[r][3] += xvk * w.w;
            }
        }
    }

#pragma unroll
    for (int r = 0; r < ROWS; ++r) {
        int gr = brow + rg * ROWS + r;
        if (gr < M) {
            float s = dinv[gr];
            float4 o;
            o.x = acc[r][0] * s; o.y = acc[r][1] * s;
            o.z = acc[r][2] * s; o.w = acc[r][3] * s;
            *(float4*)(Hout + (size_t)gr * NOUT + cc * 4) = o;
        }
    }
}

// Pull aggregation, one wave per node. V = channels per lane (2 for C=128).
template <int C, bool RELU>
__global__ __launch_bounds__(256) void aggregate_k(const float* __restrict__ H,
                                                   const int* __restrict__ offsets,
                                                   const int* __restrict__ adj,
                                                   const float* __restrict__ dinv,
                                                   const float* __restrict__ bias,
                                                   float* __restrict__ out, int n) {
    constexpr int V = C / 64;
    int wave = threadIdx.x >> 6;
    int lane = threadIdx.x & 63;
    int node = blockIdx.x * 4 + wave;
    if (node >= n) return;

    float acc[V];
    {
        const float* p = H + (size_t)node * C + lane * V;
#pragma unroll
        for (int v = 0; v < V; ++v) acc[v] = p[v];  // self-loop term hs[node]
    }
    int e0 = offsets[node], e1 = offsets[node + 1];
    int e = e0;
    for (; e + 1 < e1; e += 2) {  // unroll x2 for 2 outstanding gathers
        int s0 = adj[e], s1 = adj[e + 1];
        const float* p0 = H + (size_t)s0 * C + lane * V;
        const float* p1 = H + (size_t)s1 * C + lane * V;
        float t0[V], t1[V];
#pragma unroll
        for (int v = 0; v < V; ++v) { t0[v] = p0[v]; t1[v] = p1[v]; }
#pragma unroll
        for (int v = 0; v < V; ++v) acc[v] += t0[v] + t1[v];
    }
    if (e < e1) {
        int s0 = adj[e];
        const float* p0 = H + (size_t)s0 * C + lane * V;
#pragma unroll
        for (int v = 0; v < V; ++v) acc[v] += p0[v];
    }

    float di = dinv[node];
#pragma unroll
    for (int v = 0; v < V; ++v) {
        float r = acc[v] * di + bias[lane * V + v];
        if (RELU) r = fmaxf(r, 0.f);
        out[(size_t)node * C + lane * V + v] = r;
    }
}

extern "C" void kernel_launch(void* const* d_in, const int* in_sizes, int n_in,
                              void* d_out, int out_size, void* d_ws, size_t ws_size,
                              hipStream_t stream) {
    const float* x = (const float*)d_in[0];
    const int* ei = (const int*)d_in[1];   // harness passes integers as int32
    const float* W1 = (const float*)d_in[2];
    const float* b1 = (const float*)d_in[3];
    const float* W2 = (const float*)d_in[4];
    const float* b2 = (const float*)d_in[5];
    float* out = (float*)d_out;

    const int IN_C = 128, HID_C = 128;
    int N = in_sizes[0] / IN_C;   // 50000
    int E = in_sizes[1] / 2;      // 800000
    const int* src = ei;          // row 0
    const int* dst = ei + E;      // row 1

    // --- workspace layout (all 4B elements, 256-elem aligned) ---
    int NP = (N + 255) & ~255;
    int EP = (E + 255) & ~255;
    char* w = (char*)d_ws;
    int* counts = (int*)w;        w += (size_t)NP * 4;
    int* cursor = (int*)w;        w += (size_t)NP * 4;
    int* offsets = (int*)w;       w += (size_t)(NP + 256) * 4;
    int* bsums = (int*)w;         w += 256 * 4;
    float* dinv = (float*)w;      w += (size_t)NP * 4;
    int* adj = (int*)w;           w += (size_t)EP * 4;
    float* H1 = (float*)w;        w += (size_t)NP * HID_C * 4;  // hs1, then hs2 (reuse)
    float* HID = (float*)w;       w += (size_t)NP * HID_C * 4;  // relu'd hidden
    (void)ws_size; (void)n_in; (void)out_size;

    // counts + cursor are contiguous: one memset clears both.
    hipMemsetAsync(counts, 0, (size_t)NP * 2 * 4, stream);

    int eb = (E + 255) / 256;
    int nb = (N + 1023) / 1024;  // 49 blocks (<= 64 required by scan2)

    count_k<<<eb, 256, 0, stream>>>(dst, counts, E);
    scan1_k<<<nb, 256, 0, stream>>>(counts, offsets, bsums, dinv, N);
    scan2_k<<<1, 64, 0, stream>>>(bsums, offsets, nb, N);
    scan3_k<<<nb, 256, 0, stream>>>(offsets, bsums, N);
    fill_k<<<eb, 256, 0, stream>>>(src, dst, offsets, cursor, adj, E);

    // Layer 1: hs1 = (x @ W1) * dinv ; HID = relu(dinv * gather(hs1) + b1)
    gemm_scale_k<128><<<(N + 63) / 64, 256, 0, stream>>>(x, W1, dinv, H1, N);
    aggregate_k<128, true><<<(N + 3) / 4, 256, 0, stream>>>(H1, offsets, adj, dinv, b1, HID, N);

    // Layer 2: hs2 = (HID @ W2) * dinv ; out = dinv * gather(hs2) + b2
    gemm_scale_k<64><<<(N + 63) / 64, 256, 0, stream>>>(HID, W2, dinv, H1, N);
    aggregate_k<64, false><<<(N + 3) / 4, 256, 0, stream>>>(H1, offsets, adj, dinv, b2, out, N);
}

// Round 3
// 235.941 us; speedup vs baseline: 1.1167x; 1.1167x over previous
//
#include <hip/hip_runtime.h>
#include <hip/hip_bf16.h>

// ---------------------------------------------------------------------------
// 2-layer GCN (PyG GCNConv semantics):
//   deg[i]  = in-degree(i) + 1 (self loop);  dinv = rsqrt(deg)
//   hs      = (x @ W) * dinv[row]
//   out[d]  = dinv[d] * ( sum_{(s,d) in E} hs[s] + hs[d] ) + b    (+ relu L1)
// Pipeline: count -> scan -> CSR fill -> gemm1 -> agg1(relu) -> gemm2 -> agg2
// NOTE: harness passes integer inputs as int32 (edge_index int64 -> int*).
// Round 2: aggregate gather unrolled 8-deep for MLP (was 2) — agg was
// latency-bound at 3.36 TB/s, 18% VALU, 42% HBM.
// ---------------------------------------------------------------------------

__global__ __launch_bounds__(256) void count_k(const int* __restrict__ dst,
                                               int* __restrict__ counts, int E) {
    int e = blockIdx.x * 256 + threadIdx.x;
    if (e < E) atomicAdd(&counts[dst[e]], 1);
}

// Block-level exclusive scan: each block handles 1024 elements (4/thread).
// Also computes dinv[i] = rsqrt(counts[i] + 1).
__global__ __launch_bounds__(256) void scan1_k(const int* __restrict__ counts,
                                               int* __restrict__ offsets,
                                               int* __restrict__ bsums,
                                               float* __restrict__ dinv, int n) {
    __shared__ int sdata[256];
    int t = threadIdx.x;
    int base = blockIdx.x * 1024 + t * 4;
    int v[4];
    int s = 0;
#pragma unroll
    for (int i = 0; i < 4; ++i) {
        int idx = base + i;
        int c = (idx < n) ? counts[idx] : 0;
        v[i] = c;
        s += c;
        if (idx < n) dinv[idx] = rsqrtf((float)(c + 1));
    }
    sdata[t] = s;
    __syncthreads();
#pragma unroll
    for (int off = 1; off < 256; off <<= 1) {
        int x = 0;
        if (t >= off) x = sdata[t - off];
        __syncthreads();
        sdata[t] += x;
        __syncthreads();
    }
    int run = sdata[t] - s;  // exclusive prefix of this thread's chunk
#pragma unroll
    for (int i = 0; i < 4; ++i) {
        int idx = base + i;
        if (idx < n) offsets[idx] = run;
        run += v[i];
    }
    if (t == 255) bsums[blockIdx.x] = sdata[255];
}

// Single-block exclusive scan of the (<=64) block sums; writes offsets[n]=total.
__global__ __launch_bounds__(64) void scan2_k(int* __restrict__ bsums,
                                              int* __restrict__ offsets,
                                              int nb, int n) {
    __shared__ int sb[64];
    int t = threadIdx.x;
    int v = (t < nb) ? bsums[t] : 0;
    sb[t] = v;
    __syncthreads();
#pragma unroll
    for (int off = 1; off < 64; off <<= 1) {
        int x = 0;
        if (t >= off) x = sb[t - off];
        __syncthreads();
        sb[t] += x;
        __syncthreads();
    }
    if (t < nb) bsums[t] = sb[t] - v;      // exclusive
    if (t == nb - 1) offsets[n] = sb[t];   // total edge count
}

__global__ __launch_bounds__(256) void scan3_k(int* __restrict__ offsets,
                                               const int* __restrict__ bsums, int n) {
    int add = bsums[blockIdx.x];
    int base = blockIdx.x * 1024 + threadIdx.x * 4;
#pragma unroll
    for (int i = 0; i < 4; ++i) {
        int idx = base + i;
        if (idx < n) offsets[idx] += add;
    }
}

__global__ __launch_bounds__(256) void fill_k(const int* __restrict__ src,
                                              const int* __restrict__ dst,
                                              const int* __restrict__ offsets,
                                              int* __restrict__ cursor,
                                              int* __restrict__ adj, int E) {
    int e = blockIdx.x * 256 + threadIdx.x;
    if (e < E) {
        int d = dst[e];
        int pos = atomicAdd(&cursor[d], 1);
        adj[offsets[d] + pos] = src[e];
    }
}

// GEMM: Hout[row][c] = dinv[row] * sum_k X[row][k] * W[k][c]
// Block: 256 threads, BM=64 rows, full K=128 in LDS, 4-col x ROWS register tile.
template <int NOUT>
__global__ __launch_bounds__(256) void gemm_scale_k(const float* __restrict__ X,
                                                    const float* __restrict__ W,
                                                    const float* __restrict__ dinv,
                                                    float* __restrict__ Hout, int M) {
    constexpr int K = 128;
    constexpr int BM = 64;
    constexpr int COLCH = NOUT / 4;    // float4 column chunks: 32 or 16
    constexpr int RG = 256 / COLCH;    // row groups: 8 or 16
    constexpr int ROWS = BM / RG;      // rows per thread: 8 or 4
    __shared__ float xs[BM][K];

    int t = threadIdx.x;
    int brow = blockIdx.x * BM;

    // Stage x tile (64x128 = 2048 float4, 8 per thread), zero-pad tail rows.
    for (int i = t; i < BM * (K / 4); i += 256) {
        int row = i / (K / 4);
        int c4 = i % (K / 4);
        float4 v = make_float4(0.f, 0.f, 0.f, 0.f);
        int gr = brow + row;
        if (gr < M) v = *(const float4*)(X + (size_t)gr * K + c4 * 4);
        *(float4*)(&xs[row][c4 * 4]) = v;
    }
    __syncthreads();

    int cc = t % COLCH;
    int rg = t / COLCH;

    float acc[ROWS][4];
#pragma unroll
    for (int r = 0; r < ROWS; ++r) {
        acc[r][0] = 0.f; acc[r][1] = 0.f; acc[r][2] = 0.f; acc[r][3] = 0.f;
    }

    for (int k4 = 0; k4 < K / 4; ++k4) {
        float4 xv[ROWS];
#pragma unroll
        for (int r = 0; r < ROWS; ++r)
            xv[r] = *(const float4*)(&xs[rg * ROWS + r][k4 * 4]);
#pragma unroll
        for (int kk = 0; kk < 4; ++kk) {
            float4 w = *(const float4*)(W + (size_t)(k4 * 4 + kk) * NOUT + cc * 4);
#pragma unroll
            for (int r = 0; r < ROWS; ++r) {
                float xvk = ((const float*)&xv[r])[kk];
                acc[r][0] += xvk * w.x;
                acc[r][1] += xvk * w.y;
                acc[r][2] += xvk * w.z;
                acc[r][3] += xvk * w.w;
            }
        }
    }

#pragma unroll
    for (int r = 0; r < ROWS; ++r) {
        int gr = brow + rg * ROWS + r;
        if (gr < M) {
            float s = dinv[gr];
            float4 o;
            o.x = acc[r][0] * s; o.y = acc[r][1] * s;
            o.z = acc[r][2] * s; o.w = acc[r][3] * s;
            *(float4*)(Hout + (size_t)gr * NOUT + cc * 4) = o;
        }
    }
}

// Pull aggregation, one wave per node. V = channels per lane (2 for C=128).
// Gather unrolled 8-deep: 8 independent row loads in flight per wave.
template <int C, bool RELU>
__global__ __launch_bounds__(256) void aggregate_k(const float* __restrict__ H,
                                                   const int* __restrict__ offsets,
                                                   const int* __restrict__ adj,
                                                   const float* __restrict__ dinv,
                                                   const float* __restrict__ bias,
                                                   float* __restrict__ out, int n) {
    constexpr int V = C / 64;
    int wave = threadIdx.x >> 6;
    int lane = threadIdx.x & 63;
    int node = blockIdx.x * 4 + wave;
    if (node >= n) return;

    const float* hl = H + (size_t)lane * V;  // lane-offset base

    float acc[V];
    {
        const float* p = hl + (size_t)node * C;
#pragma unroll
        for (int v = 0; v < V; ++v) acc[v] = p[v];  // self-loop term hs[node]
    }
    int e0 = offsets[node], e1 = offsets[node + 1];
    int e = e0;

    // main: 8 edges per iter, 8 gathers outstanding
    for (; e + 8 <= e1; e += 8) {
        int s[8];
#pragma unroll
        for (int j = 0; j < 8; ++j) s[j] = adj[e + j];
        float t[8][V];
#pragma unroll
        for (int j = 0; j < 8; ++j) {
            const float* p = hl + (size_t)s[j] * C;
#pragma unroll
            for (int v = 0; v < V; ++v) t[j][v] = p[v];
        }
#pragma unroll
        for (int v = 0; v < V; ++v)
            acc[v] += ((t[0][v] + t[1][v]) + (t[2][v] + t[3][v])) +
                      ((t[4][v] + t[5][v]) + (t[6][v] + t[7][v]));
    }
    // tail: 2 edges per iter
    for (; e + 2 <= e1; e += 2) {
        int s0 = adj[e], s1 = adj[e + 1];
        const float* p0 = hl + (size_t)s0 * C;
        const float* p1 = hl + (size_t)s1 * C;
        float t0[V], t1[V];
#pragma unroll
        for (int v = 0; v < V; ++v) { t0[v] = p0[v]; t1[v] = p1[v]; }
#pragma unroll
        for (int v = 0; v < V; ++v) acc[v] += t0[v] + t1[v];
    }
    if (e < e1) {
        int s0 = adj[e];
        const float* p0 = hl + (size_t)s0 * C;
#pragma unroll
        for (int v = 0; v < V; ++v) acc[v] += p0[v];
    }

    float di = dinv[node];
#pragma unroll
    for (int v = 0; v < V; ++v) {
        float r = acc[v] * di + bias[lane * V + v];
        if (RELU) r = fmaxf(r, 0.f);
        out[(size_t)node * C + lane * V + v] = r;
    }
}

extern "C" void kernel_launch(void* const* d_in, const int* in_sizes, int n_in,
                              void* d_out, int out_size, void* d_ws, size_t ws_size,
                              hipStream_t stream) {
    const float* x = (const float*)d_in[0];
    const int* ei = (const int*)d_in[1];   // harness passes integers as int32
    const float* W1 = (const float*)d_in[2];
    const float* b1 = (const float*)d_in[3];
    const float* W2 = (const float*)d_in[4];
    const float* b2 = (const float*)d_in[5];
    float* out = (float*)d_out;

    const int IN_C = 128, HID_C = 128;
    int N = in_sizes[0] / IN_C;   // 50000
    int E = in_sizes[1] / 2;      // 800000
    const int* src = ei;          // row 0
    const int* dst = ei + E;      // row 1

    // --- workspace layout (all 4B elements, 256-elem aligned) ---
    int NP = (N + 255) & ~255;
    int EP = (E + 255) & ~255;
    char* w = (char*)d_ws;
    int* counts = (int*)w;        w += (size_t)NP * 4;
    int* cursor = (int*)w;        w += (size_t)NP * 4;
    int* offsets = (int*)w;       w += (size_t)(NP + 256) * 4;
    int* bsums = (int*)w;         w += 256 * 4;
    float* dinv = (float*)w;      w += (size_t)NP * 4;
    int* adj = (int*)w;           w += (size_t)EP * 4;
    float* H1 = (float*)w;        w += (size_t)NP * HID_C * 4;  // hs1, then hs2 (reuse)
    float* HID = (float*)w;       w += (size_t)NP * HID_C * 4;  // relu'd hidden
    (void)ws_size; (void)n_in; (void)out_size;

    // counts + cursor are contiguous: one memset clears both.
    hipMemsetAsync(counts, 0, (size_t)NP * 2 * 4, stream);

    int eb = (E + 255) / 256;
    int nb = (N + 1023) / 1024;  // 49 blocks (<= 64 required by scan2)

    count_k<<<eb, 256, 0, stream>>>(dst, counts, E);
    scan1_k<<<nb, 256, 0, stream>>>(counts, offsets, bsums, dinv, N);
    scan2_k<<<1, 64, 0, stream>>>(bsums, offsets, nb, N);
    scan3_k<<<nb, 256, 0, stream>>>(offsets, bsums, N);
    fill_k<<<eb, 256, 0, stream>>>(src, dst, offsets, cursor, adj, E);

    // Layer 1: hs1 = (x @ W1) * dinv ; HID = relu(dinv * gather(hs1) + b1)
    gemm_scale_k<128><<<(N + 63) / 64, 256, 0, stream>>>(x, W1, dinv, H1, N);
    aggregate_k<128, true><<<(N + 3) / 4, 256, 0, stream>>>(H1, offsets, adj, dinv, b1, HID, N);

    // Layer 2: hs2 = (HID @ W2) * dinv ; out = dinv * gather(hs2) + b2
    gemm_scale_k<64><<<(N + 63) / 64, 256, 0, stream>>>(HID, W2, dinv, H1, N);
    aggregate_k<64, false><<<(N + 3) / 4, 256, 0, stream>>>(H1, offsets, adj, dinv, b2, out, N);
}

// Round 4
// 200.185 us; speedup vs baseline: 1.3161x; 1.1786x over previous
//
#include <hip/hip_runtime.h>
#include <hip/hip_bf16.h>
#include <hip/hip_fp16.h>

// ---------------------------------------------------------------------------
// 2-layer GCN (PyG GCNConv semantics):
//   deg[i]  = in-degree(i) + 1 (self loop);  dinv = rsqrt(deg)
//   hs      = (x @ W) * dinv[row]        (stored fp16)
//   out[d]  = dinv[d] * ( sum_{(s,d) in E} hs[s] + hs[d] ) + b    (+ relu L1)
// Round 3 evidence: agg<128> (512B rows) == agg<64> (256B rows) == 58us ->
// gather is request/latency-bound, not byte-bound. Round 4: fp16 hidden
// storage (halve bytes+misses) + 2 nodes/wave (halve gather instructions,
// double MLP). Accuracy headroom: absmax 1.95e-3 vs 1.1e-2 threshold.
// ---------------------------------------------------------------------------

__global__ __launch_bounds__(256) void count_k(const int* __restrict__ dst,
                                               int* __restrict__ counts, int E) {
    int e = blockIdx.x * 256 + threadIdx.x;
    if (e < E) atomicAdd(&counts[dst[e]], 1);
}

// Block-level exclusive scan: each block handles 1024 elements (4/thread).
// Also computes dinv[i] = rsqrt(counts[i] + 1).
__global__ __launch_bounds__(256) void scan1_k(const int* __restrict__ counts,
                                               int* __restrict__ offsets,
                                               int* __restrict__ bsums,
                                               float* __restrict__ dinv, int n) {
    __shared__ int sdata[256];
    int t = threadIdx.x;
    int base = blockIdx.x * 1024 + t * 4;
    int v[4];
    int s = 0;
#pragma unroll
    for (int i = 0; i < 4; ++i) {
        int idx = base + i;
        int c = (idx < n) ? counts[idx] : 0;
        v[i] = c;
        s += c;
        if (idx < n) dinv[idx] = rsqrtf((float)(c + 1));
    }
    sdata[t] = s;
    __syncthreads();
#pragma unroll
    for (int off = 1; off < 256; off <<= 1) {
        int x = 0;
        if (t >= off) x = sdata[t - off];
        __syncthreads();
        sdata[t] += x;
        __syncthreads();
    }
    int run = sdata[t] - s;  // exclusive prefix of this thread's chunk
#pragma unroll
    for (int i = 0; i < 4; ++i) {
        int idx = base + i;
        if (idx < n) offsets[idx] = run;
        run += v[i];
    }
    if (t == 255) bsums[blockIdx.x] = sdata[255];
}

// Single-block exclusive scan of the (<=64) block sums; writes offsets[n]=total.
__global__ __launch_bounds__(64) void scan2_k(int* __restrict__ bsums,
                                              int* __restrict__ offsets,
                                              int nb, int n) {
    __shared__ int sb[64];
    int t = threadIdx.x;
    int v = (t < nb) ? bsums[t] : 0;
    sb[t] = v;
    __syncthreads();
#pragma unroll
    for (int off = 1; off < 64; off <<= 1) {
        int x = 0;
        if (t >= off) x = sb[t - off];
        __syncthreads();
        sb[t] += x;
        __syncthreads();
    }
    if (t < nb) bsums[t] = sb[t] - v;      // exclusive
    if (t == nb - 1) offsets[n] = sb[t];   // total edge count
}

__global__ __launch_bounds__(256) void scan3_k(int* __restrict__ offsets,
                                               const int* __restrict__ bsums, int n) {
    int add = bsums[blockIdx.x];
    int base = blockIdx.x * 1024 + threadIdx.x * 4;
#pragma unroll
    for (int i = 0; i < 4; ++i) {
        int idx = base + i;
        if (idx < n) offsets[idx] += add;
    }
}

__global__ __launch_bounds__(256) void fill_k(const int* __restrict__ src,
                                              const int* __restrict__ dst,
                                              const int* __restrict__ offsets,
                                              int* __restrict__ cursor,
                                              int* __restrict__ adj, int E) {
    int e = blockIdx.x * 256 + threadIdx.x;
    if (e < E) {
        int d = dst[e];
        int pos = atomicAdd(&cursor[d], 1);
        adj[offsets[d] + pos] = src[e];
    }
}

// GEMM: Hout[row][c] = (half) dinv[row] * sum_k X[row][k] * W[k][c]
// Block: 256 threads, BM=64 rows, full K=128 in LDS, 4-col x ROWS register tile.
template <int NOUT, bool HALF_IN>
__global__ __launch_bounds__(256) void gemm_scale_k(const void* __restrict__ Xv,
                                                    const float* __restrict__ W,
                                                    const float* __restrict__ dinv,
                                                    __half* __restrict__ Hout, int M) {
    constexpr int K = 128;
    constexpr int BM = 64;
    constexpr int COLCH = NOUT / 4;    // float4 column chunks: 32 or 16
    constexpr int RG = 256 / COLCH;    // row groups: 8 or 16
    constexpr int ROWS = BM / RG;      // rows per thread: 8 or 4
    __shared__ float xs[BM][K];

    int t = threadIdx.x;
    int brow = blockIdx.x * BM;

    if constexpr (HALF_IN) {
        const __half* X = (const __half*)Xv;
        // 8 halves (16B) per chunk: BM*K/8 = 1024 chunks, 4 per thread.
        for (int i = t; i < BM * (K / 8); i += 256) {
            int row = i / (K / 8);
            int c8 = i % (K / 8);
            int gr = brow + row;
            float f[8] = {0.f, 0.f, 0.f, 0.f, 0.f, 0.f, 0.f, 0.f};
            if (gr < M) {
                uint4 u = *(const uint4*)(X + (size_t)gr * K + c8 * 8);
                const __half2* hp = (const __half2*)&u;
#pragma unroll
                for (int j = 0; j < 4; ++j) {
                    float2 fj = __half22float2(hp[j]);
                    f[2 * j] = fj.x;
                    f[2 * j + 1] = fj.y;
                }
            }
#pragma unroll
            for (int j = 0; j < 8; ++j) xs[row][c8 * 8 + j] = f[j];
        }
    } else {
        const float* X = (const float*)Xv;
        // 64x128 floats = 2048 float4, 8 per thread; zero-pad tail rows.
        for (int i = t; i < BM * (K / 4); i += 256) {
            int row = i / (K / 4);
            int c4 = i % (K / 4);
            float4 v = make_float4(0.f, 0.f, 0.f, 0.f);
            int gr = brow + row;
            if (gr < M) v = *(const float4*)(X + (size_t)gr * K + c4 * 4);
            *(float4*)(&xs[row][c4 * 4]) = v;
        }
    }
    __syncthreads();

    int cc = t % COLCH;
    int rg = t / COLCH;

    float acc[ROWS][4];
#pragma unroll
    for (int r = 0; r < ROWS; ++r) {
        acc[r][0] = 0.f; acc[r][1] = 0.f; acc[r][2] = 0.f; acc[r][3] = 0.f;
    }

    for (int k4 = 0; k4 < K / 4; ++k4) {
        float4 xv[ROWS];
#pragma unroll
        for (int r = 0; r < ROWS; ++r)
            xv[r] = *(const float4*)(&xs[rg * ROWS + r][k4 * 4]);
#pragma unroll
        for (int kk = 0; kk < 4; ++kk) {
            float4 w = *(const float4*)(W + (size_t)(k4 * 4 + kk) * NOUT + cc * 4);
#pragma unroll
            for (int r = 0; r < ROWS; ++r) {
                float xvk = ((const float*)&xv[r])[kk];
                acc[r][0] += xvk * w.x;
                acc[r][1] += xvk * w.y;
                acc[r][2] += xvk * w.z;
                acc[r][3] += xvk * w.w;
            }
        }
    }

#pragma unroll
    for (int r = 0; r < ROWS; ++r) {
        int gr = brow + rg * ROWS + r;
        if (gr < M) {
            float s = dinv[gr];
            union { __half2 h[2]; uint2 u; } pk;
            pk.h[0] = __floats2half2_rn(acc[r][0] * s, acc[r][1] * s);
            pk.h[1] = __floats2half2_rn(acc[r][2] * s, acc[r][3] * s);
            *(uint2*)(Hout + (size_t)gr * NOUT + cc * 4) = pk.u;
        }
    }
}

// fp16 row-fragment loaders: 32 lanes cover one row.
__device__ __forceinline__ void ld_row(const __half* p, float (&f)[4]) {
    uint2 u = *(const uint2*)p;                    // 4 halves, 8B
    const __half2* hp = (const __half2*)&u;
    float2 a = __half22float2(hp[0]);
    float2 b = __half22float2(hp[1]);
    f[0] = a.x; f[1] = a.y; f[2] = b.x; f[3] = b.y;
}
__device__ __forceinline__ void ld_row(const __half* p, float (&f)[2]) {
    float2 a = __half22float2(*(const __half2*)p); // 2 halves, 4B
    f[0] = a.x; f[1] = a.y;
}

// Pull aggregation: 2 nodes per wave (one per 32-lane half-wave), 8-deep
// gather unroll => up to 16 rows in flight per wave. V = C/32 halves/lane.
template <int C, bool RELU, typename TOUT>
__global__ __launch_bounds__(256) void aggregate_k(const __half* __restrict__ H,
                                                   const int* __restrict__ offsets,
                                                   const int* __restrict__ adj,
                                                   const float* __restrict__ dinv,
                                                   const float* __restrict__ bias,
                                                   TOUT* __restrict__ out, int n) {
    constexpr int V = C / 32;
    int wave = threadIdx.x >> 6;
    int lane = threadIdx.x & 63;
    int half_id = lane >> 5;
    int sub = lane & 31;
    int node = blockIdx.x * 8 + wave * 2 + half_id;
    if (node >= n) return;

    const __half* hl = H + sub * V;  // lane-fragment base

    float acc[V];
    ld_row(hl + (size_t)node * C, acc);  // self-loop term hs[node]

    int e0 = offsets[node], e1 = offsets[node + 1];
    int e = e0;

    // main: 8 edges per iter, 8 row-gathers outstanding (x2 nodes per wave)
    for (; e + 8 <= e1; e += 8) {
        int s[8];
#pragma unroll
        for (int j = 0; j < 8; ++j) s[j] = adj[e + j];
        float t[8][V];
#pragma unroll
        for (int j = 0; j < 8; ++j) ld_row(hl + (size_t)s[j] * C, t[j]);
#pragma unroll
        for (int v = 0; v < V; ++v)
            acc[v] += ((t[0][v] + t[1][v]) + (t[2][v] + t[3][v])) +
                      ((t[4][v] + t[5][v]) + (t[6][v] + t[7][v]));
    }
    for (; e + 2 <= e1; e += 2) {
        int s0 = adj[e], s1 = adj[e + 1];
        float t0[V], t1[V];
        ld_row(hl + (size_t)s0 * C, t0);
        ld_row(hl + (size_t)s1 * C, t1);
#pragma unroll
        for (int v = 0; v < V; ++v) acc[v] += t0[v] + t1[v];
    }
    if (e < e1) {
        float t0[V];
        ld_row(hl + (size_t)adj[e] * C, t0);
#pragma unroll
        for (int v = 0; v < V; ++v) acc[v] += t0[v];
    }

    float di = dinv[node];
    float o[V];
#pragma unroll
    for (int v = 0; v < V; ++v) {
        o[v] = acc[v] * di + bias[sub * V + v];
        if (RELU) o[v] = fmaxf(o[v], 0.f);
    }

    if constexpr (sizeof(TOUT) == 2) {  // __half output (hidden layer), V==4
        union { __half2 h[2]; uint2 u; } pk;
        pk.h[0] = __floats2half2_rn(o[0], o[1]);
        pk.h[1] = __floats2half2_rn(o[2], o[3]);
        *(uint2*)((__half*)out + (size_t)node * C + sub * V) = pk.u;
    } else {  // float output (final), V==2
        *(float2*)((float*)out + (size_t)node * C + sub * V) = make_float2(o[0], o[1]);
    }
}

extern "C" void kernel_launch(void* const* d_in, const int* in_sizes, int n_in,
                              void* d_out, int out_size, void* d_ws, size_t ws_size,
                              hipStream_t stream) {
    const float* x = (const float*)d_in[0];
    const int* ei = (const int*)d_in[1];   // harness passes integers as int32
    const float* W1 = (const float*)d_in[2];
    const float* b1 = (const float*)d_in[3];
    const float* W2 = (const float*)d_in[4];
    const float* b2 = (const float*)d_in[5];
    float* out = (float*)d_out;

    const int IN_C = 128, HID_C = 128, OUT_C = 64;
    int N = in_sizes[0] / IN_C;   // 50000
    int E = in_sizes[1] / 2;      // 800000
    const int* src = ei;          // row 0
    const int* dst = ei + E;      // row 1

    // --- workspace layout (4B-aligned, 256-elem padded) ---
    int NP = (N + 255) & ~255;
    int EP = (E + 255) & ~255;
    char* w = (char*)d_ws;
    int* counts = (int*)w;      w += (size_t)NP * 4;
    int* cursor = (int*)w;      w += (size_t)NP * 4;
    int* offsets = (int*)w;     w += (size_t)(NP + 256) * 4;
    int* bsums = (int*)w;       w += 256 * 4;
    float* dinv = (float*)w;    w += (size_t)NP * 4;
    int* adj = (int*)w;         w += (size_t)EP * 4;
    __half* H1 = (__half*)w;    w += (size_t)NP * HID_C * 2;  // hs1 / hs2 (fp16)
    __half* HID = (__half*)w;   w += (size_t)NP * HID_C * 2;  // relu'd hidden (fp16)
    (void)ws_size; (void)n_in; (void)out_size; (void)OUT_C;

    // counts + cursor are contiguous: one memset clears both.
    hipMemsetAsync(counts, 0, (size_t)NP * 2 * 4, stream);

    int eb = (E + 255) / 256;
    int nb = (N + 1023) / 1024;  // 49 blocks (<= 64 required by scan2)

    count_k<<<eb, 256, 0, stream>>>(dst, counts, E);
    scan1_k<<<nb, 256, 0, stream>>>(counts, offsets, bsums, dinv, N);
    scan2_k<<<1, 64, 0, stream>>>(bsums, offsets, nb, N);
    scan3_k<<<nb, 256, 0, stream>>>(offsets, bsums, N);
    fill_k<<<eb, 256, 0, stream>>>(src, dst, offsets, cursor, adj, E);

    // Layer 1: hs1 = fp16((x @ W1) * dinv) ; HID = fp16(relu(dinv*gather + b1))
    gemm_scale_k<128, false><<<(N + 63) / 64, 256, 0, stream>>>(x, W1, dinv, H1, N);
    aggregate_k<128, true, __half><<<(N + 7) / 8, 256, 0, stream>>>(
        H1, offsets, adj, dinv, b1, HID, N);

    // Layer 2: hs2 = fp16((HID @ W2) * dinv) ; out = fp32(dinv*gather + b2)
    gemm_scale_k<64, true><<<(N + 63) / 64, 256, 0, stream>>>(HID, W2, dinv, H1, N);
    aggregate_k<64, false, float><<<(N + 7) / 8, 256, 0, stream>>>(
        H1, offsets, adj, dinv, b2, out, N);
}

// Round 5
// 172.158 us; speedup vs baseline: 1.5304x; 1.1628x over previous
//
#include <hip/hip_runtime.h>
#include <hip/hip_bf16.h>
#include <hip/hip_fp16.h>

// ---------------------------------------------------------------------------
// 2-layer GCN (PyG GCNConv semantics):
//   deg[i]  = in-degree(i) + 1 (self loop);  dinv = rsqrt(deg)
//   hs      = (x @ W) * dinv[row]        (stored fp16)
//   out[d]  = dinv[d] * ( sum_{(s,d) in E} hs[s] + hs[d] ) + b    (+ relu L1)
//
// Round 4 evidence: fill_k (random 4B scatter + random atomics) = 50us with
// 55MB HBM writes for a 3.2MB payload (17x line-amplification across 8
// non-coherent XCD L2s); count_k similar pattern ~25-30us.
// Round 5: bucketed counting sort. bucket = dst>>6 (64 nodes). Histogram is
// privatized per (bucket, blockIdx&7) so each scatter segment has a
// single-XCD writer set (blockIdx round-robins XCDs); scatter writes dense
// packed (src,dst) u32 records; finish_k builds per-bucket CSR (u16 adj),
// offsets, and dinv with LDS counts — all writes dense/coalesced.
// N=50000 < 65536 so node ids fit u16.
// ---------------------------------------------------------------------------

#define NBUCK 800           // buckets of 64 nodes: covers 51200 >= N
#define NSEG  (NBUCK * 8)   // per-(bucket, blockIdx&7) segments
#define EBLK  256           // blocks for hist/scatter (chunking must match!)

__global__ __launch_bounds__(256) void hist_k(const int* __restrict__ dst,
                                              int* __restrict__ hist,
                                              int E, int chunk) {
    __shared__ int lh[NBUCK];
    for (int i = threadIdx.x; i < NBUCK; i += 256) lh[i] = 0;
    __syncthreads();
    int lo = blockIdx.x * chunk, hi = min(E, lo + chunk);
    for (int e = lo + threadIdx.x; e < hi; e += 256)
        atomicAdd(&lh[dst[e] >> 6], 1);
    __syncthreads();
    int k = blockIdx.x & 7;
    for (int b = threadIdx.x; b < NBUCK; b += 256) {
        int c = lh[b];
        if (c) atomicAdd(&hist[b * 8 + k], c);
    }
}

// One block: exclusive scan of NSEG=6400 segment counts (25 per thread).
// Also writes segBase[NSEG]=E and offsets[N]=E.
__global__ __launch_bounds__(256) void scan_k(const int* __restrict__ hist,
                                              int* __restrict__ segBase,
                                              int* __restrict__ offsets,
                                              int N, int E) {
    __shared__ int sdata[256];
    int t = threadIdx.x;
    int base = t * 25;
    int v[25];
    int s = 0;
#pragma unroll
    for (int i = 0; i < 25; ++i) { int c = hist[base + i]; v[i] = c; s += c; }
    sdata[t] = s;
    __syncthreads();
#pragma unroll
    for (int off = 1; off < 256; off <<= 1) {
        int x = 0;
        if (t >= off) x = sdata[t - off];
        __syncthreads();
        sdata[t] += x;
        __syncthreads();
    }
    int run = sdata[t] - s;  // exclusive prefix
#pragma unroll
    for (int i = 0; i < 25; ++i) { segBase[base + i] = run; run += v[i]; }
    if (t == 255) segBase[NSEG] = run;  // == E
    if (t == 0) offsets[N] = E;
}

__global__ __launch_bounds__(256) void scatter_k(const int* __restrict__ src,
                                                 const int* __restrict__ dst,
                                                 const int* __restrict__ segBase,
                                                 int* __restrict__ gcur,
                                                 unsigned* __restrict__ rec,
                                                 int E, int chunk) {
    int k = blockIdx.x & 7;
    int lo = blockIdx.x * chunk, hi = min(E, lo + chunk);
    for (int e = lo + threadIdx.x; e < hi; e += 256) {
        int d = dst[e];
        int seg = (d >> 6) * 8 + k;
        int pos = atomicAdd(&gcur[seg], 1);
        rec[segBase[seg] + pos] = (unsigned)(src[e] & 0xffff) | ((unsigned)d << 16);
    }
}

// One block per bucket: per-node counts (LDS), dinv, offsets, u16 CSR adj.
__global__ __launch_bounds__(256) void finish_k(const unsigned* __restrict__ rec,
                                                const int* __restrict__ segBase,
                                                int* __restrict__ offsets,
                                                float* __restrict__ dinv,
                                                unsigned short* __restrict__ adj,
                                                int N) {
    __shared__ int ncnt[64], ncur[64], nodeOff[64];
    int b = blockIdx.x;
    int t = threadIdx.x;
    int segStart = segBase[b * 8];
    int segEnd = segBase[(b + 1) * 8];

    if (t < 64) { ncnt[t] = 0; ncur[t] = 0; }
    __syncthreads();

    for (int e = segStart + t; e < segEnd; e += 256)
        atomicAdd(&ncnt[(rec[e] >> 16) & 63], 1);
    __syncthreads();

    if (t == 0) {
        int r = 0;
#pragma unroll
        for (int i = 0; i < 64; ++i) { nodeOff[i] = r; r += ncnt[i]; }
    }
    __syncthreads();

    if (t < 64) {
        int gnode = b * 64 + t;
        if (gnode < N) {
            dinv[gnode] = rsqrtf((float)(ncnt[t] + 1));
            offsets[gnode] = segStart + nodeOff[t];
        }
    }
    __syncthreads();

    for (int e = segStart + t; e < segEnd; e += 256) {
        unsigned r = rec[e];
        int ln = (r >> 16) & 63;
        int p = atomicAdd(&ncur[ln], 1);
        adj[segStart + nodeOff[ln] + p] = (unsigned short)(r & 0xffff);
    }
}

// GEMM: Hout[row][c] = (half) dinv[row] * sum_k X[row][k] * W[k][c]
// Block: 256 threads, BM=64 rows, full K=128 in LDS, 4-col x ROWS register tile.
template <int NOUT, bool HALF_IN>
__global__ __launch_bounds__(256) void gemm_scale_k(const void* __restrict__ Xv,
                                                    const float* __restrict__ W,
                                                    const float* __restrict__ dinv,
                                                    __half* __restrict__ Hout, int M) {
    constexpr int K = 128;
    constexpr int BM = 64;
    constexpr int COLCH = NOUT / 4;    // float4 column chunks: 32 or 16
    constexpr int RG = 256 / COLCH;    // row groups: 8 or 16
    constexpr int ROWS = BM / RG;      // rows per thread: 8 or 4
    __shared__ float xs[BM][K];

    int t = threadIdx.x;
    int brow = blockIdx.x * BM;

    if constexpr (HALF_IN) {
        const __half* X = (const __half*)Xv;
        for (int i = t; i < BM * (K / 8); i += 256) {
            int row = i / (K / 8);
            int c8 = i % (K / 8);
            int gr = brow + row;
            float f[8] = {0.f, 0.f, 0.f, 0.f, 0.f, 0.f, 0.f, 0.f};
            if (gr < M) {
                uint4 u = *(const uint4*)(X + (size_t)gr * K + c8 * 8);
                const __half2* hp = (const __half2*)&u;
#pragma unroll
                for (int j = 0; j < 4; ++j) {
                    float2 fj = __half22float2(hp[j]);
                    f[2 * j] = fj.x;
                    f[2 * j + 1] = fj.y;
                }
            }
#pragma unroll
            for (int j = 0; j < 8; ++j) xs[row][c8 * 8 + j] = f[j];
        }
    } else {
        const float* X = (const float*)Xv;
        for (int i = t; i < BM * (K / 4); i += 256) {
            int row = i / (K / 4);
            int c4 = i % (K / 4);
            float4 v = make_float4(0.f, 0.f, 0.f, 0.f);
            int gr = brow + row;
            if (gr < M) v = *(const float4*)(X + (size_t)gr * K + c4 * 4);
            *(float4*)(&xs[row][c4 * 4]) = v;
        }
    }
    __syncthreads();

    int cc = t % COLCH;
    int rg = t / COLCH;

    float acc[ROWS][4];
#pragma unroll
    for (int r = 0; r < ROWS; ++r) {
        acc[r][0] = 0.f; acc[r][1] = 0.f; acc[r][2] = 0.f; acc[r][3] = 0.f;
    }

    for (int k4 = 0; k4 < K / 4; ++k4) {
        float4 xv[ROWS];
#pragma unroll
        for (int r = 0; r < ROWS; ++r)
            xv[r] = *(const float4*)(&xs[rg * ROWS + r][k4 * 4]);
#pragma unroll
        for (int kk = 0; kk < 4; ++kk) {
            float4 w = *(const float4*)(W + (size_t)(k4 * 4 + kk) * NOUT + cc * 4);
#pragma unroll
            for (int r = 0; r < ROWS; ++r) {
                float xvk = ((const float*)&xv[r])[kk];
                acc[r][0] += xvk * w.x;
                acc[r][1] += xvk * w.y;
                acc[r][2] += xvk * w.z;
                acc[r][3] += xvk * w.w;
            }
        }
    }

#pragma unroll
    for (int r = 0; r < ROWS; ++r) {
        int gr = brow + rg * ROWS + r;
        if (gr < M) {
            float s = dinv[gr];
            union { __half2 h[2]; uint2 u; } pk;
            pk.h[0] = __floats2half2_rn(acc[r][0] * s, acc[r][1] * s);
            pk.h[1] = __floats2half2_rn(acc[r][2] * s, acc[r][3] * s);
            *(uint2*)(Hout + (size_t)gr * NOUT + cc * 4) = pk.u;
        }
    }
}

// fp16 row-fragment loaders: 32 lanes cover one row.
__device__ __forceinline__ void ld_row(const __half* p, float (&f)[4]) {
    uint2 u = *(const uint2*)p;                    // 4 halves, 8B
    const __half2* hp = (const __half2*)&u;
    float2 a = __half22float2(hp[0]);
    float2 b = __half22float2(hp[1]);
    f[0] = a.x; f[1] = a.y; f[2] = b.x; f[3] = b.y;
}
__device__ __forceinline__ void ld_row(const __half* p, float (&f)[2]) {
    float2 a = __half22float2(*(const __half2*)p); // 2 halves, 4B
    f[0] = a.x; f[1] = a.y;
}

// Pull aggregation: 2 nodes per wave (one per 32-lane half-wave), 8-deep
// gather unroll => up to 16 rows in flight per wave. V = C/32 halves/lane.
template <int C, bool RELU, typename TOUT>
__global__ __launch_bounds__(256) void aggregate_k(const __half* __restrict__ H,
                                                   const int* __restrict__ offsets,
                                                   const unsigned short* __restrict__ adj,
                                                   const float* __restrict__ dinv,
                                                   const float* __restrict__ bias,
                                                   TOUT* __restrict__ out, int n) {
    constexpr int V = C / 32;
    int wave = threadIdx.x >> 6;
    int lane = threadIdx.x & 63;
    int half_id = lane >> 5;
    int sub = lane & 31;
    int node = blockIdx.x * 8 + wave * 2 + half_id;
    if (node >= n) return;

    const __half* hl = H + sub * V;  // lane-fragment base

    float acc[V];
    ld_row(hl + (size_t)node * C, acc);  // self-loop term hs[node]

    int e0 = offsets[node], e1 = offsets[node + 1];
    int e = e0;

    // main: 8 edges per iter, 8 row-gathers outstanding (x2 nodes per wave)
    for (; e + 8 <= e1; e += 8) {
        int s[8];
#pragma unroll
        for (int j = 0; j < 8; ++j) s[j] = adj[e + j];
        float t[8][V];
#pragma unroll
        for (int j = 0; j < 8; ++j) ld_row(hl + (size_t)s[j] * C, t[j]);
#pragma unroll
        for (int v = 0; v < V; ++v)
            acc[v] += ((t[0][v] + t[1][v]) + (t[2][v] + t[3][v])) +
                      ((t[4][v] + t[5][v]) + (t[6][v] + t[7][v]));
    }
    for (; e + 2 <= e1; e += 2) {
        int s0 = adj[e], s1 = adj[e + 1];
        float t0[V], t1[V];
        ld_row(hl + (size_t)s0 * C, t0);
        ld_row(hl + (size_t)s1 * C, t1);
#pragma unroll
        for (int v = 0; v < V; ++v) acc[v] += t0[v] + t1[v];
    }
    if (e < e1) {
        float t0[V];
        ld_row(hl + (size_t)adj[e] * C, t0);
#pragma unroll
        for (int v = 0; v < V; ++v) acc[v] += t0[v];
    }

    float di = dinv[node];
    float o[V];
#pragma unroll
    for (int v = 0; v < V; ++v) {
        o[v] = acc[v] * di + bias[sub * V + v];
        if (RELU) o[v] = fmaxf(o[v], 0.f);
    }

    if constexpr (sizeof(TOUT) == 2) {  // __half output (hidden layer), V==4
        union { __half2 h[2]; uint2 u; } pk;
        pk.h[0] = __floats2half2_rn(o[0], o[1]);
        pk.h[1] = __floats2half2_rn(o[2], o[3]);
        *(uint2*)((__half*)out + (size_t)node * C + sub * V) = pk.u;
    } else {  // float output (final), V==2
        *(float2*)((float*)out + (size_t)node * C + sub * V) = make_float2(o[0], o[1]);
    }
}

extern "C" void kernel_launch(void* const* d_in, const int* in_sizes, int n_in,
                              void* d_out, int out_size, void* d_ws, size_t ws_size,
                              hipStream_t stream) {
    const float* x = (const float*)d_in[0];
    const int* ei = (const int*)d_in[1];   // harness passes integers as int32
    const float* W1 = (const float*)d_in[2];
    const float* b1 = (const float*)d_in[3];
    const float* W2 = (const float*)d_in[4];
    const float* b2 = (const float*)d_in[5];
    float* out = (float*)d_out;

    const int IN_C = 128, HID_C = 128;
    int N = in_sizes[0] / IN_C;   // 50000
    int E = in_sizes[1] / 2;      // 800000
    const int* src = ei;          // row 0
    const int* dst = ei + E;      // row 1

    // --- workspace layout ---
    int NP = (N + 255) & ~255;
    int EP = (E + 255) & ~255;
    char* w = (char*)d_ws;
    int* hist = (int*)w;            w += (size_t)NSEG * 4;       // zeroed
    int* gcur = (int*)w;            w += (size_t)NSEG * 4;       // zeroed (contig w/ hist)
    int* segBase = (int*)w;         w += (size_t)(NSEG + 256) * 4;
    int* offsets = (int*)w;         w += (size_t)(NP + 256) * 4;
    float* dinv = (float*)w;        w += (size_t)NP * 4;
    unsigned* rec = (unsigned*)w;   w += (size_t)EP * 4;
    unsigned short* adj = (unsigned short*)w; w += (size_t)EP * 2;
    __half* H1 = (__half*)w;        w += (size_t)NP * HID_C * 2;  // hs1 / hs2 (fp16)
    __half* HID = (__half*)w;       w += (size_t)NP * HID_C * 2;  // relu'd hidden (fp16)
    (void)ws_size; (void)n_in; (void)out_size;

    // hist + gcur contiguous: one memset clears both.
    hipMemsetAsync(hist, 0, (size_t)NSEG * 2 * 4, stream);

    int chunk = (E + EBLK - 1) / EBLK;  // identical chunking for hist & scatter

    hist_k<<<EBLK, 256, 0, stream>>>(dst, hist, E, chunk);
    scan_k<<<1, 256, 0, stream>>>(hist, segBase, offsets, N, E);
    scatter_k<<<EBLK, 256, 0, stream>>>(src, dst, segBase, gcur, rec, E, chunk);
    finish_k<<<NBUCK, 256, 0, stream>>>(rec, segBase, offsets, dinv, adj, N);

    // Layer 1: hs1 = fp16((x @ W1) * dinv) ; HID = fp16(relu(dinv*gather + b1))
    gemm_scale_k<128, false><<<(N + 63) / 64, 256, 0, stream>>>(x, W1, dinv, H1, N);
    aggregate_k<128, true, __half><<<(N + 7) / 8, 256, 0, stream>>>(
        H1, offsets, adj, dinv, b1, HID, N);

    // Layer 2: hs2 = fp16((HID @ W2) * dinv) ; out = fp32(dinv*gather + b2)
    gemm_scale_k<64, true><<<(N + 63) / 64, 256, 0, stream>>>(HID, W2, dinv, H1, N);
    aggregate_k<64, false, float><<<(N + 7) / 8, 256, 0, stream>>>(
        H1, offsets, adj, dinv, b2, out, N);
}